// Round 11
// baseline (156.150 us; speedup 1.0000x reference)
//
#include <hip/hip_runtime.h>
#include <math.h>

#define N_NODES 2048
#define T_WIN 5
#define D_EMB 64
#define TOPK 21
#define B_BATCH 32
#define BN_TOTAL (B_BATCH * N_NODES)   // 65536
#define EPS_BN 1e-5f
#define NEG_SLOPE 0.2f
#define STATS_STRIDE 16

typedef unsigned long long u64;

// ---------------- wave-level helpers (wave = 64 on gfx950) ----------------
__device__ __forceinline__ float wave_sum(float v) {
#pragma unroll
    for (int off = 32; off > 0; off >>= 1) v += __shfl_xor(v, off, 64);
    return v;
}

__device__ __forceinline__ u64 max64(u64 a, u64 b) { return a > b ? a : b; }
__device__ __forceinline__ u64 min64(u64 a, u64 b) { return a < b ? a : b; }

__device__ __forceinline__ u64 bitonic_sort64_desc(u64 key, int lane) {
#pragma unroll
    for (int k = 2; k <= 64; k <<= 1) {
#pragma unroll
        for (int j = k >> 1; j >= 1; j >>= 1) {
            u64 pk = __shfl_xor(key, j, 64);
            bool dirDesc = ((lane & k) == 0);
            bool keepMax = (((lane & j) == 0) == dirDesc);
            key = keepMax ? max64(key, pk) : min64(key, pk);
        }
    }
    return key;
}

__device__ __forceinline__ u64 bitonic_merge_top64(u64 a, u64 b, int lane) {
    u64 br = __shfl(b, 63 - lane, 64);
    u64 c = max64(a, br);
#pragma unroll
    for (int j = 32; j >= 1; j >>= 1) {
        u64 pk = __shfl_xor(c, j, 64);
        bool keepMax = ((lane & j) == 0);
        c = keepMax ? max64(c, pk) : min64(c, pk);
    }
    return c;
}

// ---------------- D1: gram (blocks 0..527) | edge (blocks 528..1039) --------
// Independent stages fused into one dispatch (plain launch — the r10
// cooperative mega-kernel silently failed to launch; abandoned).
// Gram computes norms IN-TILE from its staged LDS tiles: sequential
// sum(As[d][r]^2) — identical expression everywhere a node's norm is used,
// so the symmetric write stays bit-exact. (Summation order differs from the
// old wave_sum butterfly; r4 precedent: full order change didn't flip top-k.)
__global__ __launch_bounds__(256) void k_gram_edge(
    const float* __restrict__ x, const float* __restrict__ emb,
    const float* __restrict__ W, const float* __restrict__ Wb,
    const float* __restrict__ a_src, const float* __restrict__ a_dst,
    float* __restrict__ cosM, float* __restrict__ es2T,
    float* __restrict__ ed2T, float* __restrict__ stats,
    float* __restrict__ stats2) {
    int g = blockIdx.x;
    int t = threadIdx.x;

    if (g >= 528) {
        // ================== edge part ==================
        if (g < 530) {   // stats zeroing (2 blocks x 256 x float4 = 8 KB)
            float* p = (g == 529) ? stats2 : stats;
            ((float4*)p)[t] = make_float4(0.f, 0.f, 0.f, 0.f);
        }
        int wid = t >> 6, lane = t & 63;
        int slot = (g - 528) * 4 + wid;            // 0..2047
        const float* wp = W + lane * T_WIN;
        float w0 = wp[0], w1 = wp[1], w2 = wp[2], w3 = wp[3], w4 = wp[4];
        float bias = Wb[lane];
        float as = a_src[lane], asE = a_src[D_EMB + lane];
        float ad = a_dst[lane], adE = a_dst[D_EMB + lane];
        for (int node = slot; node < BN_TOTAL; node += 2048) {
            int n = node & (N_NODES - 1);
            const float* xp = x + (size_t)node * T_WIN;
            float hv = bias + xp[0] * w0 + xp[1] * w1 + xp[2] * w2 + xp[3] * w3 + xp[4] * w4;
            float e = emb[n * D_EMB + lane];
            float es = wave_sum(hv * as + e * asE);
            float ed = wave_sum(hv * ad + e * adE);
            if (lane == 0) {
                es2T[node] = es;   // [b][n]
                ed2T[node] = ed;
            }
        }
        return;
    }

    // ================== gram part (triangle tile) ==================
    __shared__ __align__(16) float As[64][68];   // [d][i]
    __shared__ __align__(16) float Bs[64][68];   // [d][j]
    __shared__ float nIs[64], nJs[64];

    int a = (int)((sqrtf(8.f * g + 1.f) - 1.f) * 0.5f);
    while ((a + 1) * (a + 2) / 2 <= g) a++;
    while (a * (a + 1) / 2 > g) a--;
    int bq = g - a * (a + 1) / 2;
    int i0 = a * 64, j0 = bq * 64;

    {
        int r = t >> 2, c0 = t & 3;
        const float4* srcA = (const float4*)(emb + (size_t)(i0 + r) * D_EMB);
        const float4* srcB = (const float4*)(emb + (size_t)(j0 + r) * D_EMB);
#pragma unroll
        for (int k = 0; k < 4; k++) {
            int f4 = c0 + 4 * k;
            float4 v = srcA[f4];
            int d = 4 * f4;
            As[d][r] = v.x; As[d + 1][r] = v.y; As[d + 2][r] = v.z; As[d + 3][r] = v.w;
            float4 w = srcB[f4];
            Bs[d][r] = w.x; Bs[d + 1][r] = w.y; Bs[d + 2][r] = w.z; Bs[d + 3][r] = w.w;
        }
    }
    __syncthreads();

    // in-tile norms (identical expression for every occurrence of a node)
    if (t < 64) {
        float s = 0.f;
#pragma unroll
        for (int d = 0; d < 64; d++) s += As[d][t] * As[d][t];
        nIs[t] = sqrtf(s);
    } else if (t < 128) {
        int r = t - 64;
        float s = 0.f;
#pragma unroll
        for (int d = 0; d < 64; d++) s += Bs[d][r] * Bs[d][r];
        nJs[r] = sqrtf(s);
    }
    __syncthreads();

    int ti = t & 15, tj = t >> 4;
    float acc[4][4] = {};
#pragma unroll
    for (int d = 0; d < 64; d++) {
        float4 av = *(const float4*)&As[d][4 * ti];
        float4 bv = *(const float4*)&Bs[d][4 * tj];
        acc[0][0] += av.x * bv.x; acc[0][1] += av.x * bv.y; acc[0][2] += av.x * bv.z; acc[0][3] += av.x * bv.w;
        acc[1][0] += av.y * bv.x; acc[1][1] += av.y * bv.y; acc[1][2] += av.y * bv.z; acc[1][3] += av.y * bv.w;
        acc[2][0] += av.z * bv.x; acc[2][1] += av.z * bv.y; acc[2][2] += av.z * bv.z; acc[2][3] += av.z * bv.w;
        acc[3][0] += av.w * bv.x; acc[3][1] += av.w * bv.y; acc[3][2] += av.w * bv.z; acc[3][3] += av.w * bv.w;
    }

    float nis[4] = {nIs[4 * ti], nIs[4 * ti + 1], nIs[4 * ti + 2], nIs[4 * ti + 3]};
    float njs[4] = {nJs[4 * tj], nJs[4 * tj + 1], nJs[4 * tj + 2], nJs[4 * tj + 3]};
#pragma unroll
    for (int r = 0; r < 4; r++) {
        float4 o;
        o.x = acc[r][0] / (nis[r] * njs[0]);
        o.y = acc[r][1] / (nis[r] * njs[1]);
        o.z = acc[r][2] / (nis[r] * njs[2]);
        o.w = acc[r][3] / (nis[r] * njs[3]);
        int i = i0 + 4 * ti + r;
        *(float4*)(cosM + (size_t)i * N_NODES + j0 + 4 * tj) = o;
        cosM[(size_t)(j0 + 4 * tj + 0) * N_NODES + i] = o.x;
        cosM[(size_t)(j0 + 4 * tj + 1) * N_NODES + i] = o.y;
        cosM[(size_t)(j0 + 4 * tj + 2) * N_NODES + i] = o.z;
        cosM[(size_t)(j0 + 4 * tj + 3) * N_NODES + i] = o.w;
    }
}

// ---------------- D2: top-21 selection -> idxT[k][i] (verbatim r9) ----------
__global__ __launch_bounds__(256) void k_select(
    const float* __restrict__ cosM, int* __restrict__ idxT) {
    __shared__ u64 candbuf[4][128];
    int tid = threadIdx.x;
    int wid = tid >> 6, lane = tid & 63;
    int i = blockIdx.x * 4 + wid;
    const float* row = cosM + (size_t)i * N_NODES;
    u64* buf = candbuf[wid];

    u64 a = 0;
    u64 t = 0;
    int cnt = 0;
    float vcur = row[lane];

#pragma unroll 1
    for (int c = 0; c < N_NODES / 64; c++) {
        int j = c * 64 + lane;
        float v = vcur;
        if (c < N_NODES / 64 - 1) vcur = row[j + 64];
        unsigned u = __float_as_uint(v);
        u = (u & 0x80000000u) ? ~u : (u | 0x80000000u);
        u64 key = ((u64)u << 32) | (unsigned)(~j);
        unsigned long long ball = __ballot(key > t);
        if (ball) {
            int ofs = __popcll(ball & ((1ull << lane) - 1ull));
            if (key > t) buf[cnt + ofs] = key;
            cnt += (int)__popcll(ball);
            if (cnt >= 64) {
                u64 nk = buf[lane];
                nk = bitonic_sort64_desc(nk, lane);
                a = bitonic_merge_top64(a, nk, lane);
                t = __shfl(a, 20, 64);
                int rem = cnt - 64;
                u64 mv = (lane < rem) ? buf[64 + lane] : 0;
                if (lane < rem) buf[lane] = mv;
                cnt = rem;
            }
        }
    }
    while (cnt > 0) {
        int take = cnt < 64 ? cnt : 64;
        u64 nk = (lane < take) ? buf[lane] : 0;
        nk = bitonic_sort64_desc(nk, lane);
        a = bitonic_merge_top64(a, nk, lane);
        t = __shfl(a, 20, 64);
        int rem = cnt - take;
        u64 mv = (lane < rem) ? buf[take + lane] : 0;
        if (lane < rem) buf[lane] = mv;
        cnt = rem;
    }

    if (lane < TOPK) idxT[lane * N_NODES + i] = (int)(~(unsigned)a);
}

// ---------------- D3: msg + fused per-item alpha (LDS h-tile + ed2 tile) ----
// r9 k_msg gather + r9 k_alpha softmax fused per item (alpha in-register vs
// via memory is bit-identical). h-tile built from x in LDS (stride 24 B).
__global__ __launch_bounds__(256, 2) void k_msg(
    const float* __restrict__ x, const float* __restrict__ W,
    const float* __restrict__ Wb, const int* __restrict__ idxT,
    const float* __restrict__ es2T, const float* __restrict__ ed2T,
    const float* __restrict__ emb, float* __restrict__ obufT,
    float* __restrict__ stats, float* __restrict__ stats2) {
    __shared__ float hts[N_NODES][6];          // 48 KB
    __shared__ float sed[N_NODES];             // 8 KB
    __shared__ float sred[2][4][4];

    int g = blockIdx.x;                        // 512 = 32 b x 16 c
    int b = (g & 7) + 8 * ((g >> 3) & 3);      // XCD-local batches
    int c = g >> 5;
    int d0 = c * 4;
    int t = threadIdx.x;
    int wid = t >> 6, lane = t & 63;

    float wc[4][T_WIN], wb4[4];
#pragma unroll
    for (int q = 0; q < 4; q++) {
        wb4[q] = Wb[d0 + q];
#pragma unroll
        for (int tt = 0; tt < T_WIN; tt++) wc[q][tt] = W[(d0 + q) * T_WIN + tt];
    }
    {
        const float4* src = (const float4*)(ed2T + (size_t)b * N_NODES);
        float4* dst = (float4*)sed;
#pragma unroll
        for (int q = 0; q < 2; q++) dst[t + 256 * q] = src[t + 256 * q];
    }
    const float* xb = x + (size_t)b * N_NODES * T_WIN;
#pragma unroll
    for (int r = 0; r < 8; r++) {
        int row = t + 256 * r;
        const float* xr = xb + row * T_WIN;
        float x0 = xr[0], x1 = xr[1], x2 = xr[2], x3 = xr[3], x4 = xr[4];
        float h0 = wb4[0] + x0 * wc[0][0] + x1 * wc[0][1] + x2 * wc[0][2] + x3 * wc[0][3] + x4 * wc[0][4];
        float h1 = wb4[1] + x0 * wc[1][0] + x1 * wc[1][1] + x2 * wc[1][2] + x3 * wc[1][3] + x4 * wc[1][4];
        float h2 = wb4[2] + x0 * wc[2][0] + x1 * wc[2][1] + x2 * wc[2][2] + x3 * wc[2][3] + x4 * wc[2][4];
        float h3 = wb4[3] + x0 * wc[3][0] + x1 * wc[3][1] + x2 * wc[3][2] + x3 * wc[3][3] + x4 * wc[3][4];
        *(float2*)&hts[row][0] = make_float2(h0, h1);
        *(float2*)&hts[row][2] = make_float2(h2, h3);
    }
    __syncthreads();

    float sacc[4] = {0.f, 0.f, 0.f, 0.f};
    float sacc2[4] = {0.f, 0.f, 0.f, 0.f};
#pragma unroll 1
    for (int r = 0; r < 8; r++) {
        int i = 256 * r + t;
        // --- alpha (verbatim r9 k_alpha math) ---
        float es = es2T[(size_t)b * N_NODES + i];
        int jk[TOPK];
        float ev[TOPK];
        float m = -3e38f;
#pragma unroll
        for (int k = 0; k < TOPK; k++) {
            jk[k] = idxT[k * N_NODES + i];           // coalesced
            float e = es + sed[jk[k]];
            e = e > 0.f ? e : NEG_SLOPE * e;
            ev[k] = e;
            m = fmaxf(m, e);
        }
        float s = 0.f;
#pragma unroll
        for (int k = 0; k < TOPK; k++) {
            ev[k] = __expf(ev[k] - m);
            s += ev[k];
        }
        float inv = 1.0f / s;
        // --- gather (verbatim r9 k_msg) ---
        float4 z = make_float4(0.f, 0.f, 0.f, 0.f);
#pragma unroll
        for (int k = 0; k < TOPK; k++) {
            float a = ev[k] * inv;
            float2 h01 = *(const float2*)&hts[jk[k]][0];
            float2 h23 = *(const float2*)&hts[jk[k]][2];
            z.x = fmaf(a, h01.x, z.x);
            z.y = fmaf(a, h01.y, z.y);
            z.z = fmaf(a, h23.x, z.z);
            z.w = fmaf(a, h23.y, z.w);
        }
        float4 e4 = *(const float4*)(emb + (size_t)i * D_EMB + d0);
        float4 o;
        o.x = fmaxf(z.x, 0.f) * e4.x;
        o.y = fmaxf(z.y, 0.f) * e4.y;
        o.z = fmaxf(z.z, 0.f) * e4.z;
        o.w = fmaxf(z.w, 0.f) * e4.w;
        ((float4*)obufT)[((size_t)c * B_BATCH + b) * N_NODES + i] = o;
        sacc[0] += o.x; sacc[1] += o.y; sacc[2] += o.z; sacc[3] += o.w;
        sacc2[0] += o.x * o.x; sacc2[1] += o.y * o.y;
        sacc2[2] += o.z * o.z; sacc2[3] += o.w * o.w;
    }

#pragma unroll
    for (int q = 0; q < 4; q++) {
        sacc[q] = wave_sum(sacc[q]);
        sacc2[q] = wave_sum(sacc2[q]);
    }
    if (lane == 0) {
#pragma unroll
        for (int q = 0; q < 4; q++) {
            sred[0][wid][q] = sacc[q];
            sred[1][wid][q] = sacc2[q];
        }
    }
    __syncthreads();
    if (t < 8) {
        int q = t & 3, which = t >> 2;
        float v = sred[which][0][q] + sred[which][1][q] + sred[which][2][q] + sred[which][3][q];
        float* dst = which ? stats2 : stats;
        atomicAdd(&dst[(d0 + q) * STATS_STRIDE], v);
    }
}

// ---------------- D4: BN apply + relu + fc (verbatim r9) --------------------
__global__ __launch_bounds__(256) void k_out(
    const float* __restrict__ obufT, const float* __restrict__ stats,
    const float* __restrict__ stats2, const float* __restrict__ gamma,
    const float* __restrict__ beta, const float* __restrict__ fc_w,
    const float* __restrict__ fc_b, float* __restrict__ out) {
    int t = threadIdx.x;
    int wid = t >> 6, lane = t & 63;
    int nloc = lane >> 4, c = lane & 15;
    const float invM = 1.0f / (float)BN_TOTAL;

    float mean[4], inv[4], g4[4], bt4[4], fw4[4];
#pragma unroll
    for (int q = 0; q < 4; q++) {
        int d = 4 * c + q;
        float mn = stats[d * STATS_STRIDE] * invM;
        float var = stats2[d * STATS_STRIDE] * invM - mn * mn;
        mean[q] = mn;
        inv[q] = rsqrtf(var + EPS_BN);
        g4[q] = gamma[d]; bt4[q] = beta[d]; fw4[q] = fc_w[d];
    }
    float fb = fc_b[0];

#pragma unroll 1
    for (int r = 0; r < 8; r++) {
        int nd = blockIdx.x * 128 + r * 16 + wid * 4 + nloc;
        int b = nd >> 11, n = nd & (N_NODES - 1);
        float4 o = ((const float4*)obufT)[((size_t)c * B_BATCH + b) * N_NODES + n];
        float p = 0.f;
        float v;
        v = fmaxf((o.x - mean[0]) * inv[0] * g4[0] + bt4[0], 0.f); p = fmaf(v, fw4[0], p);
        v = fmaxf((o.y - mean[1]) * inv[1] * g4[1] + bt4[1], 0.f); p = fmaf(v, fw4[1], p);
        v = fmaxf((o.z - mean[2]) * inv[2] * g4[2] + bt4[2], 0.f); p = fmaf(v, fw4[2], p);
        v = fmaxf((o.w - mean[3]) * inv[3] * g4[3] + bt4[3], 0.f); p = fmaf(v, fw4[3], p);
#pragma unroll
        for (int off = 1; off <= 8; off <<= 1) p += __shfl_xor(p, off, 64);
        if (c == 0) out[nd] = p + fb;
    }
}

// ---------------- launch ----------------------------------------------------
extern "C" void kernel_launch(void* const* d_in, const int* in_sizes, int n_in,
                              void* d_out, int out_size, void* d_ws, size_t ws_size,
                              hipStream_t stream) {
    const float* x     = (const float*)d_in[0];
    const float* emb   = (const float*)d_in[1];
    const float* W     = (const float*)d_in[2];
    const float* Wb    = (const float*)d_in[3];
    const float* a_src = (const float*)d_in[4];
    const float* a_dst = (const float*)d_in[5];
    const float* gamma = (const float*)d_in[6];
    const float* beta  = (const float*)d_in[7];
    const float* fc_w  = (const float*)d_in[8];
    const float* fc_b  = (const float*)d_in[9];
    float* out = (float*)d_out;

    char* ws = (char*)d_ws;
    float* stats  = (float*)(ws + 0);             // 4 KB
    float* stats2 = (float*)(ws + 4096);          // 4 KB
    int*   idxT   = (int*)  (ws + 8192);          // 172032 B
    float* es2T   = (float*)(ws + 180224);        // 256 KB [b][n]
    float* ed2T   = (float*)(ws + 442368);        // 256 KB [b][n]
    float* cosM   = (float*)(ws + 704512);        // 16 MB (doubles as obufT)
    float* obufT  = cosM;                         // cosM dead after k_select
    // total: 17,481,728 bytes

    k_gram_edge<<<1040, 256, 0, stream>>>(x, emb, W, Wb, a_src, a_dst,
                                          cosM, es2T, ed2T, stats, stats2);
    k_select<<<N_NODES / 4, 256, 0, stream>>>(cosM, idxT);
    k_msg<<<512, 256, 0, stream>>>(x, W, Wb, idxT, es2T, ed2T, emb,
                                   obufT, stats, stats2);
    k_out<<<512, 256, 0, stream>>>(obufT, stats, stats2, gamma, beta,
                                   fc_w, fc_b, out);
}